// Round 11
// baseline (357.209 us; speedup 1.0000x reference)
//
#include <hip/hip_runtime.h>
#include <hip/hip_bf16.h>

#define NN 100000
#define NE 1200000
#define DD 64
#define EPS 1e-5f

#define NB 196                             // ceil(NN/512) dst buckets
#define GEMM_BLOCKS (NN / 32)              // 3125
#define HIST_BLOCKS 256
#define PART_BLOCKS 256
#define EPH ((NE + HIST_BLOCKS - 1) / HIST_BLOCKS)   // 4688 edges per hist slice
#define EPB ((NE + PART_BLOCKS - 1) / PART_BLOCKS)   // 4688 edges per part slice

// ---------------- GEMM tile body: fp32 compute, bf16 output ----------------
template <bool BN>
__device__ __forceinline__ void gemm_tile(const float* __restrict__ X,
                                          const float* __restrict__ W,
                                          __hip_bfloat16* __restrict__ XWh,
                                          const float* __restrict__ stats,
                                          const float* __restrict__ gamma,
                                          const float* __restrict__ beta,
                                          int blk) {
    __shared__ float xs[32][64];
    __shared__ float sc_s[64], sh_s[64];
    int col = threadIdx.x & 63;
    int rg  = threadIdx.x >> 6;            // 0..3
    int row0 = blk * 32;

    if (BN) {
        if (threadIdx.x < 64) {
            const float inv_n = 1.0f / (float)NN;
            float mu  = stats[threadIdx.x] * inv_n;
            float var = stats[64 + threadIdx.x] * inv_n - mu * mu;
            float sc  = gamma[threadIdx.x] * rsqrtf(var + EPS);
            sc_s[threadIdx.x] = sc;
            sh_s[threadIdx.x] = beta[threadIdx.x] - sc * mu;
        }
        __syncthreads();
    }

    float w[64];
#pragma unroll
    for (int k = 0; k < 64; ++k) w[k] = W[k * 64 + col];

    for (int i = threadIdx.x; i < 32 * 16; i += 256) {
        int r = i >> 4, c4 = i & 15;
        float4 v = ((const float4*)(X + (size_t)(row0 + r) * 64))[c4];
        if (BN) {
            float4 s4 = ((const float4*)sc_s)[c4];
            float4 h4 = ((const float4*)sh_s)[c4];
            v.x = s4.x * v.x + h4.x; v.x = fmaxf(v.x, 0.01f * v.x);
            v.y = s4.y * v.y + h4.y; v.y = fmaxf(v.y, 0.01f * v.y);
            v.z = s4.z * v.z + h4.z; v.z = fmaxf(v.z, 0.01f * v.z);
            v.w = s4.w * v.w + h4.w; v.w = fmaxf(v.w, 0.01f * v.w);
        }
        ((float4*)&xs[r][0])[c4] = v;
    }
    __syncthreads();

    float acc[8];
#pragma unroll
    for (int r8 = 0; r8 < 8; ++r8) {
        int r = rg * 8 + r8;
        float a = 0.0f;
#pragma unroll
        for (int k = 0; k < 64; k += 4) {
            float4 xv = *((const float4*)&xs[r][k]);
            a += xv.x * w[k] + xv.y * w[k + 1] + xv.z * w[k + 2] + xv.w * w[k + 3];
        }
        acc[r8] = a;
    }
#pragma unroll
    for (int r8 = 0; r8 < 8; ++r8)
        XWh[(size_t)(row0 + rg * 8 + r8) * 64 + col] = __float2bfloat16(acc[r8]);
}

// ---------------- fused hist + (last block) scan -> bucket offsets + cursors -----
__global__ __launch_bounds__(256) void k_histscan(const int* __restrict__ dst,
                                                  int* __restrict__ cnt196,
                                                  int* __restrict__ done,
                                                  int* __restrict__ bo,
                                                  int* __restrict__ cur) {
    __shared__ int h[NB];
    __shared__ int s[256];
    __shared__ int lastflag;
    for (int t = threadIdx.x; t < NB; t += 256) h[t] = 0;
    __syncthreads();
    int s0 = blockIdx.x * EPH;
    int s1 = s0 + EPH; if (s1 > NE) s1 = NE;
    for (int i = s0 + threadIdx.x; i < s1; i += 256)
        atomicAdd(&h[dst[i] >> 9], 1);
    __syncthreads();
    for (int t = threadIdx.x; t < NB; t += 256)
        if (h[t]) atomicAdd(&cnt196[t], h[t]);
    __threadfence();
    if (threadIdx.x == 0)
        lastflag = (atomicAdd(done, 1) == HIST_BLOCKS - 1);
    __syncthreads();
    if (lastflag) {
        int t = threadIdx.x;
        int v = (t < NB) ? atomicAdd(&cnt196[t], 0) : 0;  // atomic load (coherent)
        s[t] = v;
        __syncthreads();
        for (int o = 1; o < 256; o <<= 1) {
            int u = (t >= o) ? s[t - o] : 0;
            __syncthreads();
            s[t] += u;
            __syncthreads();
        }
        if (t < NB) {
            int ex = s[t] - v;
            bo[t] = ex;
            cur[t] = ex;
        }
        if (t == 0) bo[NB] = NE;
    }
}

// ---------------- fused: edge partition (first 256 blocks) + GEMM1 (rest) --------
__global__ __launch_bounds__(256) void k_pg(const float* __restrict__ X,
                                            const float* __restrict__ W,
                                            __hip_bfloat16* __restrict__ XWh,
                                            const int* __restrict__ src,
                                            const int* __restrict__ dst,
                                            int* __restrict__ cur,
                                            int* __restrict__ ebuf) {
    if (blockIdx.x < PART_BLOCKS) {
        __shared__ int h[NB];
        for (int t = threadIdx.x; t < NB; t += 256) h[t] = 0;
        __syncthreads();
        int s0 = blockIdx.x * EPB;
        int s1 = s0 + EPB; if (s1 > NE) s1 = NE;
        for (int i = s0 + threadIdx.x; i < s1; i += 256)
            atomicAdd(&h[dst[i] >> 9], 1);
        __syncthreads();
        for (int t = threadIdx.x; t < NB; t += 256) {
            int c = h[t];
            h[t] = c ? atomicAdd(&cur[t], c) : 0;
        }
        __syncthreads();
        for (int i = s0 + threadIdx.x; i < s1; i += 256) {
            int d = dst[i];
            int p = atomicAdd(&h[d >> 9], 1);
            ebuf[p] = src[i] | ((d & 511) << 17);
        }
    } else {
        gemm_tile<false>(X, W, XWh, nullptr, nullptr, nullptr,
                         (int)blockIdx.x - PART_BLOCKS);
    }
}

// ---------------- layer-2 GEMM with fused BN1+leaky on input ----------------
__global__ __launch_bounds__(256) void k_gemm2(const float* __restrict__ X,
                                               const float* __restrict__ W,
                                               __hip_bfloat16* __restrict__ XWh,
                                               const float* __restrict__ stats,
                                               const float* __restrict__ gamma,
                                               const float* __restrict__ beta) {
    gemm_tile<true>(X, W, XWh, stats, gamma, beta, blockIdx.x);
}

// ---------------- per-bucket: degrees -> dinv, local scan -> off, local fill -----
__global__ __launch_bounds__(512) void k_bucket(const int* __restrict__ ebuf,
                                                const int* __restrict__ bo,
                                                int* __restrict__ off,
                                                float* __restrict__ dinv,
                                                int* __restrict__ esrc) {
    __shared__ int s[512];
    int b = blockIdx.x, t = threadIdx.x;
    int base = b << 9;
    int e0 = bo[b], e1 = bo[b + 1];
    s[t] = 0;
    __syncthreads();
    for (int e = e0 + t; e < e1; e += 512)
        atomicAdd(&s[ebuf[e] >> 17], 1);
    __syncthreads();
    int deg = s[t];
    if (base + t < NN) dinv[base + t] = rsqrtf((float)deg + 1.0f);
    for (int o = 1; o < 512; o <<= 1) {
        int u = (t >= o) ? s[t - o] : 0;
        __syncthreads();
        s[t] += u;
        __syncthreads();
    }
    int gstart = e0 + s[t] - deg;
    if (base + t < NN) off[base + t] = gstart;
    if (b == NB - 1 && t == 0) off[NN] = NE;
    __syncthreads();
    s[t] = gstart;
    __syncthreads();
    for (int e = e0 + t; e < e1; e += 512) {
        int v = ebuf[e];
        int p = atomicAdd(&s[v >> 17], 1);
        esrc[p] = v & 0x1FFFF;
    }
}

// ---------------- decode 8 bf16 (uint4) -> 8 fp32 ----------------
__device__ __forceinline__ void bf16x8(uint4 u, float* f) {
    f[0] = __uint_as_float(u.x << 16);
    f[1] = __uint_as_float(u.x & 0xFFFF0000u);
    f[2] = __uint_as_float(u.y << 16);
    f[3] = __uint_as_float(u.y & 0xFFFF0000u);
    f[4] = __uint_as_float(u.z << 16);
    f[5] = __uint_as_float(u.z & 0xFFFF0000u);
    f[6] = __uint_as_float(u.w << 16);
    f[7] = __uint_as_float(u.w & 0xFFFF0000u);
}

// ---------------- aggregation + fused BN stats ----------------
// 8-lane team owns one node; lane sub holds cols [sub*8, sub*8+8) as uint4 (16B bf16).
// 4 accumulators -> up to 32 independent 128B row-gathers in flight per wave.
// After output write: shfl-reduce sums/sumsq across 8 teams/wave, LDS-combine
// 4 waves, one 128-float atomicAdd per block -> BN stats without a re-read pass.
__global__ __launch_bounds__(256) void k_agg(const __hip_bfloat16* __restrict__ XWh,
                                             const int* __restrict__ off,
                                             const int* __restrict__ esrc,
                                             const float* __restrict__ dinv,
                                             float* __restrict__ out,
                                             float* __restrict__ stats) {
    __shared__ float red[4][128];
    const uint4* __restrict__ XW4 = (const uint4*)XWh;   // row = 8 uint4 = 128B
    int team = threadIdx.x >> 3;                         // 0..31
    int sub  = threadIdx.x & 7;
    int node = blockIdx.x * 32 + team;

    float di = dinv[node];
    float a[8], b[8], c[8], d[8], r0[8], r1[8], r2[8], r3[8];
    uint4 us = XW4[(size_t)node * 8 + sub];
    bf16x8(us, a);
#pragma unroll
    for (int i = 0; i < 8; ++i) { a[i] *= di; b[i] = 0.0f; c[i] = 0.0f; d[i] = 0.0f; }

    int e0 = off[node], e1 = off[node + 1];
    int e = e0;
    for (; e + 3 < e1; e += 4) {
        int s0 = esrc[e];
        int s1 = esrc[e + 1];
        int s2 = esrc[e + 2];
        int s3 = esrc[e + 3];
        float n0 = dinv[s0], n1 = dinv[s1], n2 = dinv[s2], n3 = dinv[s3];
        uint4 u0 = XW4[(size_t)s0 * 8 + sub];
        uint4 u1 = XW4[(size_t)s1 * 8 + sub];
        uint4 u2 = XW4[(size_t)s2 * 8 + sub];
        uint4 u3 = XW4[(size_t)s3 * 8 + sub];
        bf16x8(u0, r0);
        bf16x8(u1, r1);
        bf16x8(u2, r2);
        bf16x8(u3, r3);
#pragma unroll
        for (int i = 0; i < 8; ++i) a[i] += n0 * r0[i];
#pragma unroll
        for (int i = 0; i < 8; ++i) b[i] += n1 * r1[i];
#pragma unroll
        for (int i = 0; i < 8; ++i) c[i] += n2 * r2[i];
#pragma unroll
        for (int i = 0; i < 8; ++i) d[i] += n3 * r3[i];
    }
    for (; e < e1; ++e) {
        int s0 = esrc[e];
        float n0 = dinv[s0];
        uint4 u0 = XW4[(size_t)s0 * 8 + sub];
        bf16x8(u0, r0);
#pragma unroll
        for (int i = 0; i < 8; ++i) a[i] += n0 * r0[i];
    }
#pragma unroll
    for (int i = 0; i < 8; ++i) a[i] = ((a[i] + b[i]) + (c[i] + d[i])) * di;

    float4* o4 = (float4*)out;
    o4[(size_t)node * 16 + sub * 2]     = make_float4(a[0], a[1], a[2], a[3]);
    o4[(size_t)node * 16 + sub * 2 + 1] = make_float4(a[4], a[5], a[6], a[7]);

    // ---- fused BN stats: b[] reused as sumsq ----
#pragma unroll
    for (int i = 0; i < 8; ++i) b[i] = a[i] * a[i];
#pragma unroll
    for (int m = 8; m <= 32; m <<= 1) {
#pragma unroll
        for (int i = 0; i < 8; ++i) {
            a[i] += __shfl_xor(a[i], m);
            b[i] += __shfl_xor(b[i], m);
        }
    }
    int wid = threadIdx.x >> 6;
    if ((threadIdx.x & 63) < 8) {          // team 0 of each wave holds wave totals
#pragma unroll
        for (int i = 0; i < 8; ++i) {
            red[wid][sub * 8 + i]      = a[i];
            red[wid][64 + sub * 8 + i] = b[i];
        }
    }
    __syncthreads();
    if (threadIdx.x < 128) {
        float t = red[0][threadIdx.x] + red[1][threadIdx.x] +
                  red[2][threadIdx.x] + red[3][threadIdx.x];
        atomicAdd(&stats[threadIdx.x], t);
    }
}

// ---------------- BN apply + leaky_relu (out-of-place) ----------------
__global__ __launch_bounds__(256) void k_bnact(const float* __restrict__ X,
                                               float* __restrict__ Y,
                                               const float* __restrict__ stats,
                                               const float* __restrict__ gamma,
                                               const float* __restrict__ beta,
                                               int n) {
    int lane = threadIdx.x & 63, rg = threadIdx.x >> 6;
    float inv_n = 1.0f / (float)n;
    float mu  = stats[lane] * inv_n;
    float var = stats[64 + lane] * inv_n - mu * mu;
    float sc  = gamma[lane] * rsqrtf(var + EPS);
    float sh  = beta[lane] - sc * mu;
    for (int r = blockIdx.x * 4 + rg; r < n; r += gridDim.x * 4) {
        float v = X[(size_t)r * 64 + lane];
        v = sc * v + sh;
        Y[(size_t)r * 64 + lane] = fmaxf(v, 0.01f * v);
    }
}

extern "C" void kernel_launch(void* const* d_in, const int* in_sizes, int n_in,
                              void* d_out, int out_size, void* d_ws, size_t ws_size,
                              hipStream_t stream) {
    const float* x   = (const float*)d_in[0];
    const int*   ei  = (const int*)d_in[1];
    const int*   src = ei;
    const int*   dst = ei + NE;
    const float* W1  = (const float*)d_in[2];
    const float* g1  = (const float*)d_in[4];
    const float* be1 = (const float*)d_in[5];
    const float* W2  = (const float*)d_in[6];
    const float* g2  = (const float*)d_in[8];
    const float* be2 = (const float*)d_in[9];
    float* out = (float*)d_out;

    char* ws = (char*)d_ws;
    size_t p = 0;
    auto alloc = [&](size_t bytes) {
        size_t o = p;
        p = (p + bytes + 255) & ~(size_t)255;
        return o;
    };
    int*   zeroed  = (int*)(ws + alloc(2304));                   // cnt196 | stats | done
    int*   cnt196  = zeroed;                                     // [0,196)
    float* stats   = (float*)(zeroed + 256);                     // [256, 256+256)
    int*   done    = zeroed + 512;                               // 1 int
    int*   bo      = (int*)(ws + alloc((size_t)(NB + 1) * 4));
    int*   cur     = (int*)(ws + alloc((size_t)NB * 4));
    int*   ebuf    = (int*)(ws + alloc((size_t)NE * 4));         // packed src|ld<<17
    int*   esrc    = (int*)(ws + alloc((size_t)NE * 4));
    int*   off     = (int*)(ws + alloc((size_t)(NN + 1) * 4));
    float* dinv    = (float*)(ws + alloc((size_t)NN * 4));
    __hip_bfloat16* Ah = (__hip_bfloat16*)(ws + alloc((size_t)NN * DD * 2)); // xw bf16
    float* B       = (float*)(ws + alloc((size_t)NN * DD * 4)); // raw agg fp32
    (void)ws_size; (void)in_sizes; (void)n_in; (void)out_size;

    hipMemsetAsync(zeroed, 0, 2304, stream);

    // ---- CSR build, with partition overlapped with layer-1 GEMM ----
    k_histscan<<<HIST_BLOCKS, 256, 0, stream>>>(dst, cnt196, done, bo, cur);
    k_pg<<<PART_BLOCKS + GEMM_BLOCKS, 256, 0, stream>>>(x, W1, Ah, src, dst, cur, ebuf);
    k_bucket<<<NB, 512, 0, stream>>>(ebuf, bo, off, dinv, esrc);

    // ---- layer 1: aggregation with fused BN stats ----
    k_agg<<<NN / 32, 256, 0, stream>>>(Ah, off, esrc, dinv, B, stats);

    // ---- layer 2 (BN1+leaky fused into gemm's x-load) ----
    k_gemm2<<<GEMM_BLOCKS, 256, 0, stream>>>(B, W2, Ah, stats, g1, be1);
    k_agg<<<NN / 32, 256, 0, stream>>>(Ah, off, esrc, dinv, B, stats + 128);
    k_bnact<<<1024, 256, 0, stream>>>(B, out, stats + 128, g2, be2, NN);
}

// Round 12
// 290.312 us; speedup vs baseline: 1.2304x; 1.2304x over previous
//
#include <hip/hip_runtime.h>
#include <hip/hip_bf16.h>

#define NN 100000
#define NE 1200000
#define DD 64
#define EPS 1e-5f

#define NB 196                             // ceil(NN/512) dst buckets
#define GEMM_BLOCKS (NN / 32)              // 3125
#define HIST_BLOCKS 256
#define PART_BLOCKS 256
#define EPH ((NE + HIST_BLOCKS - 1) / HIST_BLOCKS)   // 4688 edges per hist slice
#define EPB ((NE + PART_BLOCKS - 1) / PART_BLOCKS)   // 4688 edges per part slice

// ---------------- GEMM tile body: fp32 compute, bf16 output ----------------
template <bool BN>
__device__ __forceinline__ void gemm_tile(const float* __restrict__ X,
                                          const float* __restrict__ W,
                                          __hip_bfloat16* __restrict__ XWh,
                                          const float* __restrict__ stats,
                                          const float* __restrict__ gamma,
                                          const float* __restrict__ beta,
                                          int blk) {
    __shared__ float xs[32][64];
    __shared__ float sc_s[64], sh_s[64];
    int col = threadIdx.x & 63;
    int rg  = threadIdx.x >> 6;            // 0..3
    int row0 = blk * 32;

    if (BN) {
        if (threadIdx.x < 64) {
            const float inv_n = 1.0f / (float)NN;
            float mu  = stats[threadIdx.x] * inv_n;
            float var = stats[64 + threadIdx.x] * inv_n - mu * mu;
            float sc  = gamma[threadIdx.x] * rsqrtf(var + EPS);
            sc_s[threadIdx.x] = sc;
            sh_s[threadIdx.x] = beta[threadIdx.x] - sc * mu;
        }
        __syncthreads();
    }

    float w[64];
#pragma unroll
    for (int k = 0; k < 64; ++k) w[k] = W[k * 64 + col];

    for (int i = threadIdx.x; i < 32 * 16; i += 256) {
        int r = i >> 4, c4 = i & 15;
        float4 v = ((const float4*)(X + (size_t)(row0 + r) * 64))[c4];
        if (BN) {
            float4 s4 = ((const float4*)sc_s)[c4];
            float4 h4 = ((const float4*)sh_s)[c4];
            v.x = s4.x * v.x + h4.x; v.x = fmaxf(v.x, 0.01f * v.x);
            v.y = s4.y * v.y + h4.y; v.y = fmaxf(v.y, 0.01f * v.y);
            v.z = s4.z * v.z + h4.z; v.z = fmaxf(v.z, 0.01f * v.z);
            v.w = s4.w * v.w + h4.w; v.w = fmaxf(v.w, 0.01f * v.w);
        }
        ((float4*)&xs[r][0])[c4] = v;
    }
    __syncthreads();

    float acc[8];
#pragma unroll
    for (int r8 = 0; r8 < 8; ++r8) {
        int r = rg * 8 + r8;
        float a = 0.0f;
#pragma unroll
        for (int k = 0; k < 64; k += 4) {
            float4 xv = *((const float4*)&xs[r][k]);
            a += xv.x * w[k] + xv.y * w[k + 1] + xv.z * w[k + 2] + xv.w * w[k + 3];
        }
        acc[r8] = a;
    }
#pragma unroll
    for (int r8 = 0; r8 < 8; ++r8)
        XWh[(size_t)(row0 + rg * 8 + r8) * 64 + col] = __float2bfloat16(acc[r8]);
}

// ---------------- fused hist + (last block) scan -> bucket offsets + cursors -----
__global__ __launch_bounds__(256) void k_histscan(const int* __restrict__ dst,
                                                  int* __restrict__ cnt196,
                                                  int* __restrict__ done,
                                                  int* __restrict__ bo,
                                                  int* __restrict__ cur) {
    __shared__ int h[NB];
    __shared__ int s[256];
    __shared__ int lastflag;
    for (int t = threadIdx.x; t < NB; t += 256) h[t] = 0;
    __syncthreads();
    int s0 = blockIdx.x * EPH;
    int s1 = s0 + EPH; if (s1 > NE) s1 = NE;
    for (int i = s0 + threadIdx.x; i < s1; i += 256)
        atomicAdd(&h[dst[i] >> 9], 1);
    __syncthreads();
    for (int t = threadIdx.x; t < NB; t += 256)
        if (h[t]) atomicAdd(&cnt196[t], h[t]);
    __threadfence();
    if (threadIdx.x == 0)
        lastflag = (atomicAdd(done, 1) == HIST_BLOCKS - 1);
    __syncthreads();
    if (lastflag) {
        int t = threadIdx.x;
        int v = (t < NB) ? atomicAdd(&cnt196[t], 0) : 0;  // atomic load (coherent)
        s[t] = v;
        __syncthreads();
        for (int o = 1; o < 256; o <<= 1) {
            int u = (t >= o) ? s[t - o] : 0;
            __syncthreads();
            s[t] += u;
            __syncthreads();
        }
        if (t < NB) {
            int ex = s[t] - v;
            bo[t] = ex;
            cur[t] = ex;
        }
        if (t == 0) bo[NB] = NE;
    }
}

// ---------------- fused: edge partition (first 256 blocks) + GEMM1 (rest) --------
__global__ __launch_bounds__(256) void k_pg(const float* __restrict__ X,
                                            const float* __restrict__ W,
                                            __hip_bfloat16* __restrict__ XWh,
                                            const int* __restrict__ src,
                                            const int* __restrict__ dst,
                                            int* __restrict__ cur,
                                            int* __restrict__ ebuf) {
    if (blockIdx.x < PART_BLOCKS) {
        __shared__ int h[NB];
        for (int t = threadIdx.x; t < NB; t += 256) h[t] = 0;
        __syncthreads();
        int s0 = blockIdx.x * EPB;
        int s1 = s0 + EPB; if (s1 > NE) s1 = NE;
        for (int i = s0 + threadIdx.x; i < s1; i += 256)
            atomicAdd(&h[dst[i] >> 9], 1);
        __syncthreads();
        for (int t = threadIdx.x; t < NB; t += 256) {
            int c = h[t];
            h[t] = c ? atomicAdd(&cur[t], c) : 0;
        }
        __syncthreads();
        for (int i = s0 + threadIdx.x; i < s1; i += 256) {
            int d = dst[i];
            int p = atomicAdd(&h[d >> 9], 1);
            ebuf[p] = src[i] | ((d & 511) << 17);
        }
    } else {
        gemm_tile<false>(X, W, XWh, nullptr, nullptr, nullptr,
                         (int)blockIdx.x - PART_BLOCKS);
    }
}

// ---------------- layer-2 GEMM with fused BN1+leaky on input ----------------
__global__ __launch_bounds__(256) void k_gemm2(const float* __restrict__ X,
                                               const float* __restrict__ W,
                                               __hip_bfloat16* __restrict__ XWh,
                                               const float* __restrict__ stats,
                                               const float* __restrict__ gamma,
                                               const float* __restrict__ beta) {
    gemm_tile<true>(X, W, XWh, stats, gamma, beta, blockIdx.x);
}

// ---------------- per-bucket: degrees -> dinv, local scan -> off, local fill -----
__global__ __launch_bounds__(512) void k_bucket(const int* __restrict__ ebuf,
                                                const int* __restrict__ bo,
                                                int* __restrict__ off,
                                                float* __restrict__ dinv,
                                                int* __restrict__ esrc) {
    __shared__ int s[512];
    int b = blockIdx.x, t = threadIdx.x;
    int base = b << 9;
    int e0 = bo[b], e1 = bo[b + 1];
    s[t] = 0;
    __syncthreads();
    for (int e = e0 + t; e < e1; e += 512)
        atomicAdd(&s[ebuf[e] >> 17], 1);
    __syncthreads();
    int deg = s[t];
    if (base + t < NN) dinv[base + t] = rsqrtf((float)deg + 1.0f);
    for (int o = 1; o < 512; o <<= 1) {
        int u = (t >= o) ? s[t - o] : 0;
        __syncthreads();
        s[t] += u;
        __syncthreads();
    }
    int gstart = e0 + s[t] - deg;
    if (base + t < NN) off[base + t] = gstart;
    if (b == NB - 1 && t == 0) off[NN] = NE;
    __syncthreads();
    s[t] = gstart;
    __syncthreads();
    for (int e = e0 + t; e < e1; e += 512) {
        int v = ebuf[e];
        int p = atomicAdd(&s[v >> 17], 1);
        esrc[p] = v & 0x1FFFF;
    }
}

// ---------------- decode 8 bf16 (uint4) -> 8 fp32 ----------------
__device__ __forceinline__ void bf16x8(uint4 u, float* f) {
    f[0] = __uint_as_float(u.x << 16);
    f[1] = __uint_as_float(u.x & 0xFFFF0000u);
    f[2] = __uint_as_float(u.y << 16);
    f[3] = __uint_as_float(u.y & 0xFFFF0000u);
    f[4] = __uint_as_float(u.z << 16);
    f[5] = __uint_as_float(u.z & 0xFFFF0000u);
    f[6] = __uint_as_float(u.w << 16);
    f[7] = __uint_as_float(u.w & 0xFFFF0000u);
}

// ---------------- aggregation: team-per-node, 2-deep unroll (24 VGPR, proven) ----
// 8-lane team owns one node; lane sub holds cols [sub*8, sub*8+8) as uint4 (16B bf16).
// out = di * (di*row_self + sum dinv[s]*row_s), fp32.
__global__ __launch_bounds__(256) void k_agg(const __hip_bfloat16* __restrict__ XWh,
                                             const int* __restrict__ off,
                                             const int* __restrict__ esrc,
                                             const float* __restrict__ dinv,
                                             float* __restrict__ out) {
    const uint4* __restrict__ XW4 = (const uint4*)XWh;   // row = 8 uint4 = 128B
    int team = threadIdx.x >> 3;                         // 0..31
    int sub  = threadIdx.x & 7;
    int node = blockIdx.x * 32 + team;

    float di = dinv[node];
    float a[8], b[8], r0[8], r1[8];
    uint4 us = XW4[(size_t)node * 8 + sub];
    bf16x8(us, a);
#pragma unroll
    for (int i = 0; i < 8; ++i) { a[i] *= di; b[i] = 0.0f; }

    int e0 = off[node], e1 = off[node + 1];
    int e = e0;
    for (; e + 1 < e1; e += 2) {
        int s0 = esrc[e];
        int s1 = esrc[e + 1];
        float n0 = dinv[s0], n1 = dinv[s1];
        uint4 u0 = XW4[(size_t)s0 * 8 + sub];
        uint4 u1 = XW4[(size_t)s1 * 8 + sub];
        bf16x8(u0, r0);
        bf16x8(u1, r1);
#pragma unroll
        for (int i = 0; i < 8; ++i) a[i] += n0 * r0[i];
#pragma unroll
        for (int i = 0; i < 8; ++i) b[i] += n1 * r1[i];
    }
    if (e < e1) {
        int s0 = esrc[e];
        float n0 = dinv[s0];
        uint4 u0 = XW4[(size_t)s0 * 8 + sub];
        bf16x8(u0, r0);
#pragma unroll
        for (int i = 0; i < 8; ++i) a[i] += n0 * r0[i];
    }
#pragma unroll
    for (int i = 0; i < 8; ++i) a[i] = (a[i] + b[i]) * di;

    float4* o4 = (float4*)out;
    o4[(size_t)node * 16 + sub * 2]     = make_float4(a[0], a[1], a[2], a[3]);
    o4[(size_t)node * 16 + sub * 2 + 1] = make_float4(a[4], a[5], a[6], a[7]);
}

// ---------------- BN stats: column sums and sumsq ----------------
__global__ __launch_bounds__(256) void k_stats(const float* __restrict__ X,
                                               float* __restrict__ stats, int n) {
    __shared__ float ls[4][64], lq[4][64];
    int lane = threadIdx.x & 63, rg = threadIdx.x >> 6;
    float s = 0.0f, sq = 0.0f;
    for (int r = blockIdx.x * 4 + rg; r < n; r += gridDim.x * 4) {
        float v = X[(size_t)r * 64 + lane];
        s += v; sq += v * v;
    }
    ls[rg][lane] = s; lq[rg][lane] = sq;
    __syncthreads();
    if (rg == 0) {
        s  = ls[0][lane] + ls[1][lane] + ls[2][lane] + ls[3][lane];
        sq = lq[0][lane] + lq[1][lane] + lq[2][lane] + lq[3][lane];
        atomicAdd(&stats[lane], s);
        atomicAdd(&stats[64 + lane], sq);
    }
}

// ---------------- BN apply + leaky_relu (out-of-place) ----------------
__global__ __launch_bounds__(256) void k_bnact(const float* __restrict__ X,
                                               float* __restrict__ Y,
                                               const float* __restrict__ stats,
                                               const float* __restrict__ gamma,
                                               const float* __restrict__ beta,
                                               int n) {
    int lane = threadIdx.x & 63, rg = threadIdx.x >> 6;
    float inv_n = 1.0f / (float)n;
    float mu  = stats[lane] * inv_n;
    float var = stats[64 + lane] * inv_n - mu * mu;
    float sc  = gamma[lane] * rsqrtf(var + EPS);
    float sh  = beta[lane] - sc * mu;
    for (int r = blockIdx.x * 4 + rg; r < n; r += gridDim.x * 4) {
        float v = X[(size_t)r * 64 + lane];
        v = sc * v + sh;
        Y[(size_t)r * 64 + lane] = fmaxf(v, 0.01f * v);
    }
}

extern "C" void kernel_launch(void* const* d_in, const int* in_sizes, int n_in,
                              void* d_out, int out_size, void* d_ws, size_t ws_size,
                              hipStream_t stream) {
    const float* x   = (const float*)d_in[0];
    const int*   ei  = (const int*)d_in[1];
    const int*   src = ei;
    const int*   dst = ei + NE;
    const float* W1  = (const float*)d_in[2];
    const float* g1  = (const float*)d_in[4];
    const float* be1 = (const float*)d_in[5];
    const float* W2  = (const float*)d_in[6];
    const float* g2  = (const float*)d_in[8];
    const float* be2 = (const float*)d_in[9];
    float* out = (float*)d_out;

    char* ws = (char*)d_ws;
    size_t p = 0;
    auto alloc = [&](size_t bytes) {
        size_t o = p;
        p = (p + bytes + 255) & ~(size_t)255;
        return o;
    };
    int*   zeroed  = (int*)(ws + alloc(2304));                   // cnt196 | stats | done
    int*   cnt196  = zeroed;                                     // [0,196)
    float* stats   = (float*)(zeroed + 256);                     // [256, 256+256)
    int*   done    = zeroed + 512;                               // 1 int
    int*   bo      = (int*)(ws + alloc((size_t)(NB + 1) * 4));
    int*   cur     = (int*)(ws + alloc((size_t)NB * 4));
    int*   ebuf    = (int*)(ws + alloc((size_t)NE * 4));         // packed src|ld<<17
    int*   esrc    = (int*)(ws + alloc((size_t)NE * 4));
    int*   off     = (int*)(ws + alloc((size_t)(NN + 1) * 4));
    float* dinv    = (float*)(ws + alloc((size_t)NN * 4));
    __hip_bfloat16* Ah = (__hip_bfloat16*)(ws + alloc((size_t)NN * DD * 2)); // xw bf16
    float* B       = (float*)(ws + alloc((size_t)NN * DD * 4)); // raw agg fp32
    (void)ws_size; (void)in_sizes; (void)n_in; (void)out_size;

    hipMemsetAsync(zeroed, 0, 2304, stream);

    // ---- CSR build, with partition overlapped with layer-1 GEMM ----
    k_histscan<<<HIST_BLOCKS, 256, 0, stream>>>(dst, cnt196, done, bo, cur);
    k_pg<<<PART_BLOCKS + GEMM_BLOCKS, 256, 0, stream>>>(x, W1, Ah, src, dst, cur, ebuf);
    k_bucket<<<NB, 512, 0, stream>>>(ebuf, bo, off, dinv, esrc);

    // ---- layer 1 aggregation + stats ----
    k_agg<<<NN / 32, 256, 0, stream>>>(Ah, off, esrc, dinv, B);
    k_stats<<<512, 256, 0, stream>>>(B, stats, NN);

    // ---- layer 2 (BN1+leaky fused into gemm's x-load) ----
    k_gemm2<<<GEMM_BLOCKS, 256, 0, stream>>>(B, W2, Ah, stats, g1, be1);
    k_agg<<<NN / 32, 256, 0, stream>>>(Ah, off, esrc, dinv, B);
    k_stats<<<512, 256, 0, stream>>>(B, stats + 128, NN);
    k_bnact<<<1024, 256, 0, stream>>>(B, out, stats + 128, g2, be2, NN);
}

// Round 13
// 280.446 us; speedup vs baseline: 1.2737x; 1.0352x over previous
//
#include <hip/hip_runtime.h>
#include <hip/hip_bf16.h>

#define NN 100000
#define NE 1200000
#define DD 64
#define EPS 1e-5f

#define NB 196                             // ceil(NN/512) dst buckets
#define GEMM_BLOCKS ((NN + 63) / 64)       // 1563 (64 rows/block)
#define HIST_BLOCKS 256
#define PART_BLOCKS 256
#define EPH ((NE + HIST_BLOCKS - 1) / HIST_BLOCKS)   // 4688 edges per hist slice
#define EPB ((NE + PART_BLOCKS - 1) / PART_BLOCKS)   // 4688 edges per part slice

typedef short bf16x8_t __attribute__((ext_vector_type(8)));
typedef float f32x4_t  __attribute__((ext_vector_type(4)));

__device__ __forceinline__ short f2bf(float f) {
    __hip_bfloat16 h = __float2bfloat16(f);
    return reinterpret_cast<short&>(h);
}
__device__ __forceinline__ float bf2f(short s) {
    return __uint_as_float(((unsigned)(unsigned short)s) << 16);
}

// ---------------- MFMA GEMM tile: 64 rows x 64 cols, fp32-in (split bf16), bf16-out --
// x split into hi+lo bf16 (error ~2^-17); W single bf16 (error ~ output staging level).
// A/B frags: row = lane&15, k = (lane>>4)*8+j (contiguous bf16x8 in LDS).
// C/D: col = lane&15, row = (lane>>4)*4 + reg  [verified m89].
template <bool BN>
__device__ __forceinline__ void gemm_tile(const float* __restrict__ X,
                                          const float* __restrict__ W,
                                          __hip_bfloat16* __restrict__ XWh,
                                          const float* __restrict__ stats,
                                          const float* __restrict__ gamma,
                                          const float* __restrict__ beta,
                                          int blk) {
    __shared__ __align__(16) short xhi[64 * 72];   // row stride 72 (pad 8) -> 2-way banks
    __shared__ __align__(16) short xlo[64 * 72];
    __shared__ __align__(16) short wt[64 * 72];    // Wt[n][k] (B^T row-major)
    __shared__ float sc_s[64], sh_s[64];
    int t = threadIdx.x;
    int row0 = blk * 64;

    if (BN) {
        if (t < 64) {
            const float inv_n = 1.0f / (float)NN;
            float mu  = stats[t] * inv_n;
            float var = stats[64 + t] * inv_n - mu * mu;
            float sc  = gamma[t] * rsqrtf(var + EPS);
            sc_s[t] = sc;
            sh_s[t] = beta[t] - sc * mu;
        }
        __syncthreads();
    }

    // stage W transposed as bf16: Wt[n][k] (one-time, 16 elems/thread)
    for (int i = t; i < 64 * 64; i += 256) {
        int k = i >> 6, n = i & 63;
        wt[n * 72 + k] = f2bf(W[k * 64 + n]);
    }

    // stage x tile: 1024 float4, 4 per thread, split hi/lo
    for (int it = 0; it < 4; ++it) {
        int i = it * 256 + t;
        int r = i >> 4, c4 = i & 15;
        int grow = row0 + r;
        float4 v = make_float4(0.f, 0.f, 0.f, 0.f);
        if (grow < NN) v = ((const float4*)(X + (size_t)grow * 64))[c4];
        if (BN) {
            float4 s4 = ((const float4*)sc_s)[c4];
            float4 h4 = ((const float4*)sh_s)[c4];
            v.x = s4.x * v.x + h4.x; v.x = fmaxf(v.x, 0.01f * v.x);
            v.y = s4.y * v.y + h4.y; v.y = fmaxf(v.y, 0.01f * v.y);
            v.z = s4.z * v.z + h4.z; v.z = fmaxf(v.z, 0.01f * v.z);
            v.w = s4.w * v.w + h4.w; v.w = fmaxf(v.w, 0.01f * v.w);
        }
        short h0 = f2bf(v.x), h1 = f2bf(v.y), h2 = f2bf(v.z), h3 = f2bf(v.w);
        short l0 = f2bf(v.x - bf2f(h0)), l1 = f2bf(v.y - bf2f(h1));
        short l2 = f2bf(v.z - bf2f(h2)), l3 = f2bf(v.w - bf2f(h3));
        int base = r * 72 + c4 * 4;
        *(short4*)&xhi[base] = make_short4(h0, h1, h2, h3);
        *(short4*)&xlo[base] = make_short4(l0, l1, l2, l3);
    }
    __syncthreads();

    int w = t >> 6;                 // wave 0..3 -> rows w*16..w*16+15
    int l = t & 63;
    int fr = l & 15;                // frag row/col
    int fq = l >> 4;                // frag quarter
    int abase = (w * 16 + fr) * 72 + fq * 8;

    bf16x8_t ahi0 = *(const bf16x8_t*)&xhi[abase];
    bf16x8_t ahi1 = *(const bf16x8_t*)&xhi[abase + 32];
    bf16x8_t alo0 = *(const bf16x8_t*)&xlo[abase];
    bf16x8_t alo1 = *(const bf16x8_t*)&xlo[abase + 32];

    f32x4_t acc[4];
#pragma unroll
    for (int c = 0; c < 4; ++c) acc[c] = (f32x4_t){0.f, 0.f, 0.f, 0.f};

#pragma unroll
    for (int c = 0; c < 4; ++c) {
        int bbase = (c * 16 + fr) * 72 + fq * 8;
        bf16x8_t b0 = *(const bf16x8_t*)&wt[bbase];
        bf16x8_t b1 = *(const bf16x8_t*)&wt[bbase + 32];
        acc[c] = __builtin_amdgcn_mfma_f32_16x16x32_bf16(ahi0, b0, acc[c], 0, 0, 0);
        acc[c] = __builtin_amdgcn_mfma_f32_16x16x32_bf16(alo0, b0, acc[c], 0, 0, 0);
        acc[c] = __builtin_amdgcn_mfma_f32_16x16x32_bf16(ahi1, b1, acc[c], 0, 0, 0);
        acc[c] = __builtin_amdgcn_mfma_f32_16x16x32_bf16(alo1, b1, acc[c], 0, 0, 0);
    }

#pragma unroll
    for (int c = 0; c < 4; ++c) {
#pragma unroll
        for (int i = 0; i < 4; ++i) {
            int grow = row0 + w * 16 + fq * 4 + i;
            if (grow < NN)
                XWh[(size_t)grow * 64 + c * 16 + fr] = __float2bfloat16(acc[c][i]);
        }
    }
}

// ---------------- fused hist + (last block) scan -> bucket offsets + cursors -----
__global__ __launch_bounds__(256) void k_histscan(const int* __restrict__ dst,
                                                  int* __restrict__ cnt196,
                                                  int* __restrict__ done,
                                                  int* __restrict__ bo,
                                                  int* __restrict__ cur) {
    __shared__ int h[NB];
    __shared__ int s[256];
    __shared__ int lastflag;
    for (int t = threadIdx.x; t < NB; t += 256) h[t] = 0;
    __syncthreads();
    int s0 = blockIdx.x * EPH;
    int s1 = s0 + EPH; if (s1 > NE) s1 = NE;
    for (int i = s0 + threadIdx.x; i < s1; i += 256)
        atomicAdd(&h[dst[i] >> 9], 1);
    __syncthreads();
    for (int t = threadIdx.x; t < NB; t += 256)
        if (h[t]) atomicAdd(&cnt196[t], h[t]);
    __threadfence();
    if (threadIdx.x == 0)
        lastflag = (atomicAdd(done, 1) == HIST_BLOCKS - 1);
    __syncthreads();
    if (lastflag) {
        int t = threadIdx.x;
        int v = (t < NB) ? atomicAdd(&cnt196[t], 0) : 0;  // atomic load (coherent)
        s[t] = v;
        __syncthreads();
        for (int o = 1; o < 256; o <<= 1) {
            int u = (t >= o) ? s[t - o] : 0;
            __syncthreads();
            s[t] += u;
            __syncthreads();
        }
        if (t < NB) {
            int ex = s[t] - v;
            bo[t] = ex;
            cur[t] = ex;
        }
        if (t == 0) bo[NB] = NE;
    }
}

// ---------------- fused: edge partition (first 256 blocks) + GEMM1 (rest) --------
__global__ __launch_bounds__(256) void k_pg(const float* __restrict__ X,
                                            const float* __restrict__ W,
                                            __hip_bfloat16* __restrict__ XWh,
                                            const int* __restrict__ src,
                                            const int* __restrict__ dst,
                                            int* __restrict__ cur,
                                            int* __restrict__ ebuf) {
    if (blockIdx.x < PART_BLOCKS) {
        __shared__ int h[NB];
        for (int t = threadIdx.x; t < NB; t += 256) h[t] = 0;
        __syncthreads();
        int s0 = blockIdx.x * EPB;
        int s1 = s0 + EPB; if (s1 > NE) s1 = NE;
        for (int i = s0 + threadIdx.x; i < s1; i += 256)
            atomicAdd(&h[dst[i] >> 9], 1);
        __syncthreads();
        for (int t = threadIdx.x; t < NB; t += 256) {
            int c = h[t];
            h[t] = c ? atomicAdd(&cur[t], c) : 0;
        }
        __syncthreads();
        for (int i = s0 + threadIdx.x; i < s1; i += 256) {
            int d = dst[i];
            int p = atomicAdd(&h[d >> 9], 1);
            ebuf[p] = src[i] | ((d & 511) << 17);
        }
    } else {
        gemm_tile<false>(X, W, XWh, nullptr, nullptr, nullptr,
                         (int)blockIdx.x - PART_BLOCKS);
    }
}

// ---------------- layer-2 GEMM with fused BN1+leaky on input ----------------
__global__ __launch_bounds__(256) void k_gemm2(const float* __restrict__ X,
                                               const float* __restrict__ W,
                                               __hip_bfloat16* __restrict__ XWh,
                                               const float* __restrict__ stats,
                                               const float* __restrict__ gamma,
                                               const float* __restrict__ beta) {
    gemm_tile<true>(X, W, XWh, stats, gamma, beta, blockIdx.x);
}

// ---------------- per-bucket: degrees -> dinv, local scan -> off, local fill -----
__global__ __launch_bounds__(512) void k_bucket(const int* __restrict__ ebuf,
                                                const int* __restrict__ bo,
                                                int* __restrict__ off,
                                                float* __restrict__ dinv,
                                                int* __restrict__ esrc) {
    __shared__ int s[512];
    int b = blockIdx.x, t = threadIdx.x;
    int base = b << 9;
    int e0 = bo[b], e1 = bo[b + 1];
    s[t] = 0;
    __syncthreads();
    for (int e = e0 + t; e < e1; e += 512)
        atomicAdd(&s[ebuf[e] >> 17], 1);
    __syncthreads();
    int deg = s[t];
    if (base + t < NN) dinv[base + t] = rsqrtf((float)deg + 1.0f);
    for (int o = 1; o < 512; o <<= 1) {
        int u = (t >= o) ? s[t - o] : 0;
        __syncthreads();
        s[t] += u;
        __syncthreads();
    }
    int gstart = e0 + s[t] - deg;
    if (base + t < NN) off[base + t] = gstart;
    if (b == NB - 1 && t == 0) off[NN] = NE;
    __syncthreads();
    s[t] = gstart;
    __syncthreads();
    for (int e = e0 + t; e < e1; e += 512) {
        int v = ebuf[e];
        int p = atomicAdd(&s[v >> 17], 1);
        esrc[p] = v & 0x1FFFF;
    }
}

// ---------------- decode 8 bf16 (uint4) -> 8 fp32 ----------------
__device__ __forceinline__ void bf16x8d(uint4 u, float* f) {
    f[0] = __uint_as_float(u.x << 16);
    f[1] = __uint_as_float(u.x & 0xFFFF0000u);
    f[2] = __uint_as_float(u.y << 16);
    f[3] = __uint_as_float(u.y & 0xFFFF0000u);
    f[4] = __uint_as_float(u.z << 16);
    f[5] = __uint_as_float(u.z & 0xFFFF0000u);
    f[6] = __uint_as_float(u.w << 16);
    f[7] = __uint_as_float(u.w & 0xFFFF0000u);
}

// ---------------- aggregation: team-per-node, 2-deep unroll (proven 24 VGPR) -----
__global__ __launch_bounds__(256) void k_agg(const __hip_bfloat16* __restrict__ XWh,
                                             const int* __restrict__ off,
                                             const int* __restrict__ esrc,
                                             const float* __restrict__ dinv,
                                             float* __restrict__ out) {
    const uint4* __restrict__ XW4 = (const uint4*)XWh;   // row = 8 uint4 = 128B
    int team = threadIdx.x >> 3;                         // 0..31
    int sub  = threadIdx.x & 7;
    int node = blockIdx.x * 32 + team;

    float di = dinv[node];
    float a[8], b[8], r0[8], r1[8];
    uint4 us = XW4[(size_t)node * 8 + sub];
    bf16x8d(us, a);
#pragma unroll
    for (int i = 0; i < 8; ++i) { a[i] *= di; b[i] = 0.0f; }

    int e0 = off[node], e1 = off[node + 1];
    int e = e0;
    for (; e + 1 < e1; e += 2) {
        int s0 = esrc[e];
        int s1 = esrc[e + 1];
        float n0 = dinv[s0], n1 = dinv[s1];
        uint4 u0 = XW4[(size_t)s0 * 8 + sub];
        uint4 u1 = XW4[(size_t)s1 * 8 + sub];
        bf16x8d(u0, r0);
        bf16x8d(u1, r1);
#pragma unroll
        for (int i = 0; i < 8; ++i) a[i] += n0 * r0[i];
#pragma unroll
        for (int i = 0; i < 8; ++i) b[i] += n1 * r1[i];
    }
    if (e < e1) {
        int s0 = esrc[e];
        float n0 = dinv[s0];
        uint4 u0 = XW4[(size_t)s0 * 8 + sub];
        bf16x8d(u0, r0);
#pragma unroll
        for (int i = 0; i < 8; ++i) a[i] += n0 * r0[i];
    }
#pragma unroll
    for (int i = 0; i < 8; ++i) a[i] = (a[i] + b[i]) * di;

    float4* o4 = (float4*)out;
    o4[(size_t)node * 16 + sub * 2]     = make_float4(a[0], a[1], a[2], a[3]);
    o4[(size_t)node * 16 + sub * 2 + 1] = make_float4(a[4], a[5], a[6], a[7]);
}

// ---------------- BN stats: column sums and sumsq ----------------
__global__ __launch_bounds__(256) void k_stats(const float* __restrict__ X,
                                               float* __restrict__ stats, int n) {
    __shared__ float ls[4][64], lq[4][64];
    int lane = threadIdx.x & 63, rg = threadIdx.x >> 6;
    float s = 0.0f, sq = 0.0f;
    for (int r = blockIdx.x * 4 + rg; r < n; r += gridDim.x * 4) {
        float v = X[(size_t)r * 64 + lane];
        s += v; sq += v * v;
    }
    ls[rg][lane] = s; lq[rg][lane] = sq;
    __syncthreads();
    if (rg == 0) {
        s  = ls[0][lane] + ls[1][lane] + ls[2][lane] + ls[3][lane];
        sq = lq[0][lane] + lq[1][lane] + lq[2][lane] + lq[3][lane];
        atomicAdd(&stats[lane], s);
        atomicAdd(&stats[64 + lane], sq);
    }
}

// ---------------- BN apply + leaky_relu (out-of-place) ----------------
__global__ __launch_bounds__(256) void k_bnact(const float* __restrict__ X,
                                               float* __restrict__ Y,
                                               const float* __restrict__ stats,
                                               const float* __restrict__ gamma,
                                               const float* __restrict__ beta,
                                               int n) {
    int lane = threadIdx.x & 63, rg = threadIdx.x >> 6;
    float inv_n = 1.0f / (float)n;
    float mu  = stats[lane] * inv_n;
    float var = stats[64 + lane] * inv_n - mu * mu;
    float sc  = gamma[lane] * rsqrtf(var + EPS);
    float sh  = beta[lane] - sc * mu;
    for (int r = blockIdx.x * 4 + rg; r < n; r += gridDim.x * 4) {
        float v = X[(size_t)r * 64 + lane];
        v = sc * v + sh;
        Y[(size_t)r * 64 + lane] = fmaxf(v, 0.01f * v);
    }
}

extern "C" void kernel_launch(void* const* d_in, const int* in_sizes, int n_in,
                              void* d_out, int out_size, void* d_ws, size_t ws_size,
                              hipStream_t stream) {
    const float* x   = (const float*)d_in[0];
    const int*   ei  = (const int*)d_in[1];
    const int*   src = ei;
    const int*   dst = ei + NE;
    const float* W1  = (const float*)d_in[2];
    const float* g1  = (const float*)d_in[4];
    const float* be1 = (const float*)d_in[5];
    const float* W2  = (const float*)d_in[6];
    const float* g2  = (const float*)d_in[8];
    const float* be2 = (const float*)d_in[9];
    float* out = (float*)d_out;

    char* ws = (char*)d_ws;
    size_t p = 0;
    auto alloc = [&](size_t bytes) {
        size_t o = p;
        p = (p + bytes + 255) & ~(size_t)255;
        return o;
    };
    int*   zeroed  = (int*)(ws + alloc(2304));                   // cnt196 | stats | done
    int*   cnt196  = zeroed;                                     // [0,196)
    float* stats   = (float*)(zeroed + 256);                     // [256, 256+256)
    int*   done    = zeroed + 512;                               // 1 int
    int*   bo      = (int*)(ws + alloc((size_t)(NB + 1) * 4));
    int*   cur     = (int*)(ws + alloc((size_t)NB * 4));
    int*   ebuf    = (int*)(ws + alloc((size_t)NE * 4));         // packed src|ld<<17
    int*   esrc    = (int*)(ws + alloc((size_t)NE * 4));
    int*   off     = (int*)(ws + alloc((size_t)(NN + 1) * 4));
    float* dinv    = (float*)(ws + alloc((size_t)NN * 4));
    __hip_bfloat16* Ah = (__hip_bfloat16*)(ws + alloc((size_t)NN * DD * 2)); // xw bf16
    float* B       = (float*)(ws + alloc((size_t)NN * DD * 4)); // raw agg fp32
    (void)ws_size; (void)in_sizes; (void)n_in; (void)out_size;

    hipMemsetAsync(zeroed, 0, 2304, stream);

    // ---- CSR build, with partition overlapped with layer-1 GEMM ----
    k_histscan<<<HIST_BLOCKS, 256, 0, stream>>>(dst, cnt196, done, bo, cur);
    k_pg<<<PART_BLOCKS + GEMM_BLOCKS, 256, 0, stream>>>(x, W1, Ah, src, dst, cur, ebuf);
    k_bucket<<<NB, 512, 0, stream>>>(ebuf, bo, off, dinv, esrc);

    // ---- layer 1 aggregation + stats ----
    k_agg<<<NN / 32, 256, 0, stream>>>(Ah, off, esrc, dinv, B);
    k_stats<<<512, 256, 0, stream>>>(B, stats, NN);

    // ---- layer 2 (BN1+leaky fused into gemm's x-load) ----
    k_gemm2<<<GEMM_BLOCKS, 256, 0, stream>>>(B, W2, Ah, stats, g1, be1);
    k_agg<<<NN / 32, 256, 0, stream>>>(Ah, off, esrc, dinv, B);
    k_stats<<<512, 256, 0, stream>>>(B, stats + 128, NN);
    k_bnact<<<1024, 256, 0, stream>>>(B, out, stats + 128, g2, be2, NN);
}

// Round 14
// 262.019 us; speedup vs baseline: 1.3633x; 1.0703x over previous
//
#include <hip/hip_runtime.h>
#include <hip/hip_bf16.h>

#define NN 100000
#define NE 1200000
#define DD 64
#define EPS 1e-5f

#define NB 196                             // ceil(NN/512) dst buckets
#define GEMM_BLOCKS ((NN + 63) / 64)       // 1563 (64 rows/block)
#define HIST_BLOCKS 256
#define PART_BLOCKS 512
#define EPH ((NE + HIST_BLOCKS - 1) / HIST_BLOCKS)   // 4688 edges per hist slice
#define EPB ((NE + PART_BLOCKS - 1) / PART_BLOCKS)   // 2344 edges per part slice

typedef short bf16x8_t __attribute__((ext_vector_type(8)));
typedef float f32x4_t  __attribute__((ext_vector_type(4)));

__device__ __forceinline__ short f2bf(float f) {
    __hip_bfloat16 h = __float2bfloat16(f);
    return reinterpret_cast<short&>(h);
}
__device__ __forceinline__ float bf2f(short s) {
    return __uint_as_float(((unsigned)(unsigned short)s) << 16);
}
__device__ __forceinline__ unsigned packbf(float f0, float f1) {
    return ((unsigned)(unsigned short)f2bf(f0)) |
           (((unsigned)(unsigned short)f2bf(f1)) << 16);
}

// ---------------- MFMA GEMM tile: 64 rows x 64 cols ----------------
// BN=false: X fp32, split hi+lo bf16 (x error ~2^-17), 16 MFMAs.
// BN=true:  X bf16 (Bh), BN-affine+leaky applied during staging, 8 MFMAs.
// A/B frags: row = lane&15, k = (lane>>4)*8+j. C/D: col = lane&15, row = (lane>>4)*4+reg.
template <bool BN>
__device__ __forceinline__ void gemm_tile(const void* __restrict__ Xv,
                                          const float* __restrict__ W,
                                          __hip_bfloat16* __restrict__ XWh,
                                          const float* __restrict__ stats,
                                          const float* __restrict__ gamma,
                                          const float* __restrict__ beta,
                                          int blk) {
    __shared__ __align__(16) short xhi[64 * 72];   // row stride 72 (pad 8)
    __shared__ __align__(16) short xlo[64 * 72];   // unused in BN path
    __shared__ __align__(16) short wt[64 * 72];    // Wt[n][k] (B^T row-major)
    __shared__ float sc_s[64], sh_s[64];
    int t = threadIdx.x;
    int row0 = blk * 64;

    if (BN) {
        if (t < 64) {
            const float inv_n = 1.0f / (float)NN;
            float mu  = stats[t] * inv_n;
            float var = stats[64 + t] * inv_n - mu * mu;
            float sc  = gamma[t] * rsqrtf(var + EPS);
            sc_s[t] = sc;
            sh_s[t] = beta[t] - sc * mu;
        }
        __syncthreads();
    }

    // stage W transposed as bf16: Wt[n][k]
    for (int i = t; i < 64 * 64; i += 256) {
        int k = i >> 6, n = i & 63;
        wt[n * 72 + k] = f2bf(W[k * 64 + n]);
    }

    if (BN) {
        const unsigned* Xb = (const unsigned*)Xv;   // bf16 pairs, 32 per row
        for (int it = 0; it < 8; ++it) {
            int i = it * 256 + t;
            int r = i >> 5, cu = i & 31;
            int grow = row0 + r;
            float f0 = 0.f, f1 = 0.f;
            if (grow < NN) {
                unsigned u = Xb[(size_t)grow * 32 + cu];
                f0 = __uint_as_float(u << 16);
                f1 = __uint_as_float(u & 0xFFFF0000u);
            }
            f0 = sc_s[cu * 2] * f0 + sh_s[cu * 2];       f0 = fmaxf(f0, 0.01f * f0);
            f1 = sc_s[cu * 2 + 1] * f1 + sh_s[cu * 2 + 1]; f1 = fmaxf(f1, 0.01f * f1);
            *(unsigned*)&xhi[r * 72 + cu * 2] = packbf(f0, f1);
        }
    } else {
        const float* Xf = (const float*)Xv;
        for (int it = 0; it < 4; ++it) {
            int i = it * 256 + t;
            int r = i >> 4, c4 = i & 15;
            int grow = row0 + r;
            float4 v = make_float4(0.f, 0.f, 0.f, 0.f);
            if (grow < NN) v = ((const float4*)(Xf + (size_t)grow * 64))[c4];
            short h0 = f2bf(v.x), h1 = f2bf(v.y), h2 = f2bf(v.z), h3 = f2bf(v.w);
            short l0 = f2bf(v.x - bf2f(h0)), l1 = f2bf(v.y - bf2f(h1));
            short l2 = f2bf(v.z - bf2f(h2)), l3 = f2bf(v.w - bf2f(h3));
            int base = r * 72 + c4 * 4;
            *(short4*)&xhi[base] = make_short4(h0, h1, h2, h3);
            *(short4*)&xlo[base] = make_short4(l0, l1, l2, l3);
        }
    }
    __syncthreads();

    int w = t >> 6;                 // wave 0..3 -> rows w*16..w*16+15
    int l = t & 63;
    int fr = l & 15;
    int fq = l >> 4;
    int abase = (w * 16 + fr) * 72 + fq * 8;

    bf16x8_t ahi0 = *(const bf16x8_t*)&xhi[abase];
    bf16x8_t ahi1 = *(const bf16x8_t*)&xhi[abase + 32];
    bf16x8_t alo0, alo1;
    if (!BN) {
        alo0 = *(const bf16x8_t*)&xlo[abase];
        alo1 = *(const bf16x8_t*)&xlo[abase + 32];
    }

    f32x4_t acc[4];
#pragma unroll
    for (int c = 0; c < 4; ++c) acc[c] = (f32x4_t){0.f, 0.f, 0.f, 0.f};

#pragma unroll
    for (int c = 0; c < 4; ++c) {
        int bbase = (c * 16 + fr) * 72 + fq * 8;
        bf16x8_t b0 = *(const bf16x8_t*)&wt[bbase];
        bf16x8_t b1 = *(const bf16x8_t*)&wt[bbase + 32];
        acc[c] = __builtin_amdgcn_mfma_f32_16x16x32_bf16(ahi0, b0, acc[c], 0, 0, 0);
        acc[c] = __builtin_amdgcn_mfma_f32_16x16x32_bf16(ahi1, b1, acc[c], 0, 0, 0);
        if (!BN) {
            acc[c] = __builtin_amdgcn_mfma_f32_16x16x32_bf16(alo0, b0, acc[c], 0, 0, 0);
            acc[c] = __builtin_amdgcn_mfma_f32_16x16x32_bf16(alo1, b1, acc[c], 0, 0, 0);
        }
    }

#pragma unroll
    for (int c = 0; c < 4; ++c) {
#pragma unroll
        for (int i = 0; i < 4; ++i) {
            int grow = row0 + w * 16 + fq * 4 + i;
            if (grow < NN)
                XWh[(size_t)grow * 64 + c * 16 + fr] = __float2bfloat16(acc[c][i]);
        }
    }
}

// ---------------- fused hist + (last block) scan -> bucket offsets + cursors -----
__global__ __launch_bounds__(256) void k_histscan(const int* __restrict__ dst,
                                                  int* __restrict__ cnt196,
                                                  int* __restrict__ done,
                                                  int* __restrict__ bo,
                                                  int* __restrict__ cur) {
    __shared__ int h[NB];
    __shared__ int s[256];
    __shared__ int lastflag;
    for (int t = threadIdx.x; t < NB; t += 256) h[t] = 0;
    __syncthreads();
    int s0 = blockIdx.x * EPH;
    int s1 = s0 + EPH; if (s1 > NE) s1 = NE;
    for (int i = s0 + threadIdx.x; i < s1; i += 256)
        atomicAdd(&h[dst[i] >> 9], 1);
    __syncthreads();
    for (int t = threadIdx.x; t < NB; t += 256)
        if (h[t]) atomicAdd(&cnt196[t], h[t]);
    __threadfence();
    if (threadIdx.x == 0)
        lastflag = (atomicAdd(done, 1) == HIST_BLOCKS - 1);
    __syncthreads();
    if (lastflag) {
        int t = threadIdx.x;
        int v = (t < NB) ? atomicAdd(&cnt196[t], 0) : 0;  // atomic load (coherent)
        s[t] = v;
        __syncthreads();
        for (int o = 1; o < 256; o <<= 1) {
            int u = (t >= o) ? s[t - o] : 0;
            __syncthreads();
            s[t] += u;
            __syncthreads();
        }
        if (t < NB) {
            int ex = s[t] - v;
            bo[t] = ex;
            cur[t] = ex;
        }
        if (t == 0) bo[NB] = NE;
    }
}

// ---------------- fused: edge partition (first 512 blocks) + GEMM1 (rest) --------
__global__ __launch_bounds__(256) void k_pg(const float* __restrict__ X,
                                            const float* __restrict__ W,
                                            __hip_bfloat16* __restrict__ XWh,
                                            const int* __restrict__ src,
                                            const int* __restrict__ dst,
                                            int* __restrict__ cur,
                                            int* __restrict__ ebuf) {
    if (blockIdx.x < PART_BLOCKS) {
        __shared__ int h[NB];
        for (int t = threadIdx.x; t < NB; t += 256) h[t] = 0;
        __syncthreads();
        int s0 = blockIdx.x * EPB;
        int s1 = s0 + EPB; if (s1 > NE) s1 = NE;
        for (int i = s0 + threadIdx.x; i < s1; i += 256)
            atomicAdd(&h[dst[i] >> 9], 1);
        __syncthreads();
        for (int t = threadIdx.x; t < NB; t += 256) {
            int c = h[t];
            h[t] = c ? atomicAdd(&cur[t], c) : 0;
        }
        __syncthreads();
        for (int i = s0 + threadIdx.x; i < s1; i += 256) {
            int d = dst[i];
            int p = atomicAdd(&h[d >> 9], 1);
            ebuf[p] = src[i] | ((d & 511) << 17);
        }
    } else {
        gemm_tile<false>(X, W, XWh, nullptr, nullptr, nullptr,
                         (int)blockIdx.x - PART_BLOCKS);
    }
}

// ---------------- layer-2 GEMM: bf16 input, fused BN1+leaky ----------------
__global__ __launch_bounds__(256) void k_gemm2(const __hip_bfloat16* __restrict__ X,
                                               const float* __restrict__ W,
                                               __hip_bfloat16* __restrict__ XWh,
                                               const float* __restrict__ stats,
                                               const float* __restrict__ gamma,
                                               const float* __restrict__ beta) {
    gemm_tile<true>(X, W, XWh, stats, gamma, beta, blockIdx.x);
}

// ---------------- per-bucket: degrees -> dinv, local scan -> off, local fill -----
__global__ __launch_bounds__(512) void k_bucket(const int* __restrict__ ebuf,
                                                const int* __restrict__ bo,
                                                int* __restrict__ off,
                                                float* __restrict__ dinv,
                                                int* __restrict__ esrc) {
    __shared__ int s[512];
    int b = blockIdx.x, t = threadIdx.x;
    int base = b << 9;
    int e0 = bo[b], e1 = bo[b + 1];
    s[t] = 0;
    __syncthreads();
    for (int e = e0 + t; e < e1; e += 512)
        atomicAdd(&s[ebuf[e] >> 17], 1);
    __syncthreads();
    int deg = s[t];
    if (base + t < NN) dinv[base + t] = rsqrtf((float)deg + 1.0f);
    for (int o = 1; o < 512; o <<= 1) {
        int u = (t >= o) ? s[t - o] : 0;
        __syncthreads();
        s[t] += u;
        __syncthreads();
    }
    int gstart = e0 + s[t] - deg;
    if (base + t < NN) off[base + t] = gstart;
    if (b == NB - 1 && t == 0) off[NN] = NE;
    __syncthreads();
    s[t] = gstart;
    __syncthreads();
    for (int e = e0 + t; e < e1; e += 512) {
        int v = ebuf[e];
        int p = atomicAdd(&s[v >> 17], 1);
        esrc[p] = v & 0x1FFFF;
    }
}

// ---------------- decode 8 bf16 (uint4) -> 8 fp32 ----------------
__device__ __forceinline__ void bf16x8d(uint4 u, float* f) {
    f[0] = __uint_as_float(u.x << 16);
    f[1] = __uint_as_float(u.x & 0xFFFF0000u);
    f[2] = __uint_as_float(u.y << 16);
    f[3] = __uint_as_float(u.y & 0xFFFF0000u);
    f[4] = __uint_as_float(u.z << 16);
    f[5] = __uint_as_float(u.z & 0xFFFF0000u);
    f[6] = __uint_as_float(u.w << 16);
    f[7] = __uint_as_float(u.w & 0xFFFF0000u);
}

// ---------------- aggregation: team-per-node, 2-deep unroll, bf16 in/out --------
__global__ __launch_bounds__(256) void k_agg(const __hip_bfloat16* __restrict__ XWh,
                                             const int* __restrict__ off,
                                             const int* __restrict__ esrc,
                                             const float* __restrict__ dinv,
                                             __hip_bfloat16* __restrict__ outh) {
    const uint4* __restrict__ XW4 = (const uint4*)XWh;   // row = 8 uint4 = 128B
    int team = threadIdx.x >> 3;                         // 0..31
    int sub  = threadIdx.x & 7;
    int node = blockIdx.x * 32 + team;

    float di = dinv[node];
    float a[8], b[8], r0[8], r1[8];
    uint4 us = XW4[(size_t)node * 8 + sub];
    bf16x8d(us, a);
#pragma unroll
    for (int i = 0; i < 8; ++i) { a[i] *= di; b[i] = 0.0f; }

    int e0 = off[node], e1 = off[node + 1];
    int e = e0;
    for (; e + 1 < e1; e += 2) {
        int s0 = esrc[e];
        int s1 = esrc[e + 1];
        float n0 = dinv[s0], n1 = dinv[s1];
        uint4 u0 = XW4[(size_t)s0 * 8 + sub];
        uint4 u1 = XW4[(size_t)s1 * 8 + sub];
        bf16x8d(u0, r0);
        bf16x8d(u1, r1);
#pragma unroll
        for (int i = 0; i < 8; ++i) a[i] += n0 * r0[i];
#pragma unroll
        for (int i = 0; i < 8; ++i) b[i] += n1 * r1[i];
    }
    if (e < e1) {
        int s0 = esrc[e];
        float n0 = dinv[s0];
        uint4 u0 = XW4[(size_t)s0 * 8 + sub];
        bf16x8d(u0, r0);
#pragma unroll
        for (int i = 0; i < 8; ++i) a[i] += n0 * r0[i];
    }
#pragma unroll
    for (int i = 0; i < 8; ++i) a[i] = (a[i] + b[i]) * di;

    uint4 ob;
    ob.x = packbf(a[0], a[1]);
    ob.y = packbf(a[2], a[3]);
    ob.z = packbf(a[4], a[5]);
    ob.w = packbf(a[6], a[7]);
    ((uint4*)outh)[(size_t)node * 8 + sub] = ob;
}

// ---------------- BN stats over bf16 matrix: column sums and sumsq --------------
__global__ __launch_bounds__(256) void k_stats(const __hip_bfloat16* __restrict__ Xh,
                                               float* __restrict__ stats, int n) {
    __shared__ float ls[8][64], lq[8][64];
    const unsigned* X = (const unsigned*)Xh;             // 32 col-pairs per row
    int c  = threadIdx.x & 31;                           // col pair
    int rg = threadIdx.x >> 5;                           // 0..7
    float s0 = 0.f, q0 = 0.f, s1 = 0.f, q1 = 0.f;
    for (int r = blockIdx.x * 8 + rg; r < n; r += gridDim.x * 8) {
        unsigned u = X[(size_t)r * 32 + c];
        float f0 = __uint_as_float(u << 16);
        float f1 = __uint_as_float(u & 0xFFFF0000u);
        s0 += f0; q0 += f0 * f0;
        s1 += f1; q1 += f1 * f1;
    }
    ls[rg][c * 2] = s0; ls[rg][c * 2 + 1] = s1;
    lq[rg][c * 2] = q0; lq[rg][c * 2 + 1] = q1;
    __syncthreads();
    if (threadIdx.x < 64) {
        int t = threadIdx.x;
        float s = 0.f;
#pragma unroll
        for (int g = 0; g < 8; ++g) s += ls[g][t];
        atomicAdd(&stats[t], s);
    } else if (threadIdx.x < 128) {
        int t = threadIdx.x - 64;
        float q = 0.f;
#pragma unroll
        for (int g = 0; g < 8; ++g) q += lq[g][t];
        atomicAdd(&stats[64 + t], q);
    }
}

// ---------------- BN apply + leaky_relu: bf16 in, fp32 out ----------------
__global__ __launch_bounds__(256) void k_bnact(const __hip_bfloat16* __restrict__ Xh,
                                               float* __restrict__ Y,
                                               const float* __restrict__ stats,
                                               const float* __restrict__ gamma,
                                               const float* __restrict__ beta,
                                               int n) {
    const unsigned* X = (const unsigned*)Xh;
    int c  = threadIdx.x & 31;
    int rg = threadIdx.x >> 5;
    float inv_n = 1.0f / (float)n;
    float mu0  = stats[c * 2] * inv_n;
    float mu1  = stats[c * 2 + 1] * inv_n;
    float var0 = stats[64 + c * 2] * inv_n - mu0 * mu0;
    float var1 = stats[64 + c * 2 + 1] * inv_n - mu1 * mu1;
    float sc0  = gamma[c * 2] * rsqrtf(var0 + EPS);
    float sc1  = gamma[c * 2 + 1] * rsqrtf(var1 + EPS);
    float sh0  = beta[c * 2] - sc0 * mu0;
    float sh1  = beta[c * 2 + 1] - sc1 * mu1;
    for (int r = blockIdx.x * 8 + rg; r < n; r += gridDim.x * 8) {
        unsigned u = X[(size_t)r * 32 + c];
        float f0 = __uint_as_float(u << 16);
        float f1 = __uint_as_float(u & 0xFFFF0000u);
        f0 = sc0 * f0 + sh0; f0 = fmaxf(f0, 0.01f * f0);
        f1 = sc1 * f1 + sh1; f1 = fmaxf(f1, 0.01f * f1);
        ((float2*)Y)[(size_t)r * 32 + c] = make_float2(f0, f1);
    }
}

extern "C" void kernel_launch(void* const* d_in, const int* in_sizes, int n_in,
                              void* d_out, int out_size, void* d_ws, size_t ws_size,
                              hipStream_t stream) {
    const float* x   = (const float*)d_in[0];
    const int*   ei  = (const int*)d_in[1];
    const int*   src = ei;
    const int*   dst = ei + NE;
    const float* W1  = (const float*)d_in[2];
    const float* g1  = (const float*)d_in[4];
    const float* be1 = (const float*)d_in[5];
    const float* W2  = (const float*)d_in[6];
    const float* g2  = (const float*)d_in[8];
    const float* be2 = (const float*)d_in[9];
    float* out = (float*)d_out;

    char* ws = (char*)d_ws;
    size_t p = 0;
    auto alloc = [&](size_t bytes) {
        size_t o = p;
        p = (p + bytes + 255) & ~(size_t)255;
        return o;
    };
    int*   zeroed  = (int*)(ws + alloc(2304));                   // cnt196 | stats | done
    int*   cnt196  = zeroed;                                     // [0,196)
    float* stats   = (float*)(zeroed + 256);                     // 256 floats
    int*   done    = zeroed + 512;                               // 1 int
    int*   bo      = (int*)(ws + alloc((size_t)(NB + 1) * 4));
    int*   cur     = (int*)(ws + alloc((size_t)NB * 4));
    int*   ebuf    = (int*)(ws + alloc((size_t)NE * 4));         // packed src|ld<<17
    int*   esrc    = (int*)(ws + alloc((size_t)NE * 4));
    int*   off     = (int*)(ws + alloc((size_t)(NN + 1) * 4));
    float* dinv    = (float*)(ws + alloc((size_t)NN * 4));
    __hip_bfloat16* Ah = (__hip_bfloat16*)(ws + alloc((size_t)NN * DD * 2)); // xw bf16
    __hip_bfloat16* Bh = (__hip_bfloat16*)(ws + alloc((size_t)NN * DD * 2)); // agg bf16
    (void)ws_size; (void)in_sizes; (void)n_in; (void)out_size;

    hipMemsetAsync(zeroed, 0, 2304, stream);

    // ---- CSR build, with partition overlapped with layer-1 GEMM ----
    k_histscan<<<HIST_BLOCKS, 256, 0, stream>>>(dst, cnt196, done, bo, cur);
    k_pg<<<PART_BLOCKS + GEMM_BLOCKS, 256, 0, stream>>>(x, W1, Ah, src, dst, cur, ebuf);
    k_bucket<<<NB, 512, 0, stream>>>(ebuf, bo, off, dinv, esrc);

    // ---- layer 1 aggregation + stats ----
    k_agg<<<NN / 32, 256, 0, stream>>>(Ah, off, esrc, dinv, Bh);
    k_stats<<<512, 256, 0, stream>>>(Bh, stats, NN);

    // ---- layer 2 (BN1+leaky fused into gemm's bf16 x-load) ----
    k_gemm2<<<GEMM_BLOCKS, 256, 0, stream>>>(Bh, W2, Ah, stats, g1, be1);
    k_agg<<<NN / 32, 256, 0, stream>>>(Ah, off, esrc, dinv, Bh);
    k_stats<<<512, 256, 0, stream>>>(Bh, stats + 128, NN);
    k_bnact<<<1024, 256, 0, stream>>>(Bh, out, stats + 128, g2, be2, NN);
}